// Round 1
// baseline (1269.085 us; speedup 1.0000x reference)
//
#include <hip/hip_runtime.h>
#include <hip/hip_bf16.h>

#define DIM 128
#define NT  2048
#define K5_EDGES 32
#define TT 64
#define NN 64

static constexpr float SQRT_D      = 11.313708498984761f;   // sqrt(128)
static constexpr float INV_SQRT_DK = 0.08838834764831845f;  // 1/sqrt(128)
static constexpr float LN_EPS      = 1e-5f;

__device__ __forceinline__ float waveReduceSum(float v) {
#pragma unroll
    for (int off = 32; off > 0; off >>= 1) v += __shfl_xor(v, off, 64);
    return v;
}

// K1: x = emb[iid]*sqrt(D); qkv = LN1(x).  One wave per node.
__global__ __launch_bounds__(256) void k_qkv(
    const int* __restrict__ iid, const float* __restrict__ emb,
    const float* __restrict__ w, const float* __restrict__ b,
    float* __restrict__ qkv, int Ni)
{
    int wid  = blockIdx.x * 4 + (threadIdx.x >> 6);
    int lane = threadIdx.x & 63;
    if (wid >= Ni) return;
    int id = iid[wid];
    float2 e2 = *(const float2*)(emb + (size_t)id * DIM + lane * 2);
    float x0 = e2.x * SQRT_D, x1 = e2.y * SQRT_D;
    float m = waveReduceSum(x0 + x1) * (1.0f / DIM);
    float d0 = x0 - m, d1 = x1 - m;
    float v = waveReduceSum(d0 * d0 + d1 * d1) * (1.0f / DIM);
    float r = rsqrtf(v + LN_EPS);
    float2 wv = *(const float2*)(w + lane * 2);
    float2 bv = *(const float2*)(b + lane * 2);
    float2 o = make_float2(d0 * r * wv.x + bv.x, d1 * r * wv.y + bv.y);
    *(float2*)(qkv + (size_t)wid * DIM + lane * 2) = o;
}

// K2: 8-edge attention + residual + LN2 -> ft.  One wave per node.
__global__ __launch_bounds__(256) void k_attn(
    const int* __restrict__ iid, const int* __restrict__ inter_src,
    const float* __restrict__ emb, const float* __restrict__ qkv,
    const float* __restrict__ w, const float* __restrict__ b,
    float* __restrict__ ft, int Ni)
{
    int wid  = blockIdx.x * 4 + (threadIdx.x >> 6);
    int lane = threadIdx.x & 63;
    if (wid >= Ni) return;
    float2 q = *(const float2*)(qkv + (size_t)wid * DIM + lane * 2);
    int srcv = 0;
    if (lane < 8) srcv = inter_src[wid + lane * Ni];
    float2 kv[8];
#pragma unroll
    for (int j = 0; j < 8; ++j) {
        int s = __shfl(srcv, j, 64);
        kv[j] = *(const float2*)(qkv + (size_t)s * DIM + lane * 2);
    }
    float p[8];
#pragma unroll
    for (int j = 0; j < 8; ++j) p[j] = q.x * kv[j].x + q.y * kv[j].y;
#pragma unroll
    for (int off = 32; off > 0; off >>= 1) {
#pragma unroll
        for (int j = 0; j < 8; ++j) p[j] += __shfl_xor(p[j], off, 64);
    }
    float wx = 0.f, wy = 0.f, z = 0.f;
#pragma unroll
    for (int j = 0; j < 8; ++j) {
        float sc = __expf(fminf(fmaxf(p[j] * INV_SQRT_DK, -10.0f), 10.0f));
        wx += sc * kv[j].x; wy += sc * kv[j].y; z += sc;
    }
    float rz = 1.0f / z;
    int id = iid[wid];
    float2 e2 = *(const float2*)(emb + (size_t)id * DIM + lane * 2);
    float y0 = e2.x * SQRT_D + wx * rz;
    float y1 = e2.y * SQRT_D + wy * rz;
    float m = waveReduceSum(y0 + y1) * (1.0f / DIM);
    float d0 = y0 - m, d1 = y1 - m;
    float v = waveReduceSum(d0 * d0 + d1 * d1) * (1.0f / DIM);
    float r = rsqrtf(v + LN_EPS);
    float2 wv2 = *(const float2*)(w + lane * 2);
    float2 bv2 = *(const float2*)(b + lane * 2);
    float2 o = make_float2(d0 * r * wv2.x + bv2.x, d1 * r * wv2.y + bv2.y);
    *(float2*)(ft + (size_t)wid * DIM + lane * 2) = o;
}

// K3: per-target mean of gathered ft rows.  One block per target, 4 waves split k.
__global__ __launch_bounds__(256) void k_mean(
    const int* __restrict__ agg_src, const float* __restrict__ ft,
    float* __restrict__ meanb, int Ea)
{
    int t = blockIdx.x;
    int wv = threadIdx.x >> 6, lane = threadIdx.x & 63;
    int cnt = (Ea - t + NT - 1) / NT;
    float ax = 0.f, ay = 0.f;
    for (int k = wv; k < cnt; k += 4) {
        int e = t + k * NT;
        int src = agg_src[e];
        float2 vv = *(const float2*)(ft + (size_t)src * DIM + lane * 2);
        ax += vv.x; ay += vv.y;
    }
    __shared__ float red[4][DIM];
    red[wv][lane * 2] = ax; red[wv][lane * 2 + 1] = ay;
    __syncthreads();
    if (wv == 0) {
        float sx = red[0][lane*2] + red[1][lane*2] + red[2][lane*2] + red[3][lane*2];
        float sy = red[0][lane*2+1] + red[1][lane*2+1] + red[2][lane*2+1] + red[3][lane*2+1];
        float inv = 1.0f / (float)(cnt > 0 ? cnt : 1);
        *(float2*)(meanb + (size_t)t * DIM + lane * 2) = make_float2(sx * inv, sy * inv);
    }
}

// K4: f[t] = concat(target_emb, mean[t]) @ Wr.   2 targets per 256-thread block.
__global__ __launch_bounds__(256) void k_f(
    const float* __restrict__ meanb, const float* __restrict__ te,
    const float* __restrict__ Wr, float* __restrict__ f)
{
    int t = blockIdx.x * 2 + (threadIdx.x >> 7);
    int j = threadIdx.x & 127;
    float acc = 0.f;
#pragma unroll 4
    for (int k = 0; k < DIM; ++k) acc += te[k] * Wr[k * DIM + j];
    const float* mrow = meanb + (size_t)t * DIM;
#pragma unroll 4
    for (int k = 0; k < DIM; ++k) acc += mrow[k] * Wr[(DIM + k) * DIM + j];
    f[(size_t)t * DIM + j] = acc;
}

// K5: per-edge  s[e] = sum_j tanh( [ft_e,pos] @ Wq )_j * f[e%NT][j]
// 32 edges per block; A staged in LDS; Wq streamed through LDS in 64-row chunks.
__global__ __launch_bounds__(256) void k_edge(
    const int* __restrict__ agg_src, const int* __restrict__ agg_pid,
    const float* __restrict__ ft, const float* __restrict__ pos,
    const float* __restrict__ Wq, const float* __restrict__ f,
    float* __restrict__ sgl, int Ea)
{
    __shared__ float A[K5_EDGES][260];   // 256 + pad(4); row = 1040B (16B aligned)
    __shared__ float W[64][132];         // row = 528B (16B aligned)
    int tid = threadIdx.x;
    int e0 = blockIdx.x * K5_EDGES;
    {   // stage A: [ft_e | pos] per edge
        int g = tid >> 6;          // 0..3
        int c = (tid & 63) * 4;    // 0..252
#pragma unroll
        for (int rr = 0; rr < 8; ++rr) {
            int eL = g * 8 + rr;
            int e = e0 + eL;
            float4 v = make_float4(0.f, 0.f, 0.f, 0.f);
            if (e < Ea) {
                if (c < DIM) v = *(const float4*)(ft  + (size_t)agg_src[e] * DIM + c);
                else         v = *(const float4*)(pos + (size_t)agg_pid[e] * DIM + (c - DIM));
            }
            *(float4*)&A[eL][c] = v;
        }
    }
    int e4 = tid >> 5;   // 0..7  -> edges e4*4 .. +3
    int j4 = tid & 31;   // 0..31 -> cols  j4*4 .. +3
    float acc[4][4] = {};
    for (int kc = 0; kc < 2 * DIM; kc += 64) {
        __syncthreads();
        {   // stage Wq rows kc..kc+63
            int row = tid >> 5;        // 0..7
            int c4  = (tid & 31) * 4;
#pragma unroll
            for (int rr = 0; rr < 8; ++rr) {
                int r = rr * 8 + row;
                *(float4*)&W[r][c4] = *(const float4*)(Wq + (size_t)(kc + r) * DIM + c4);
            }
        }
        __syncthreads();
#pragma unroll 2
        for (int kk = 0; kk < 64; kk += 4) {
            float4 a[4], wv[4];
#pragma unroll
            for (int i = 0; i < 4; ++i) a[i]  = *(const float4*)&A[e4 * 4 + i][kc + kk];
#pragma unroll
            for (int u = 0; u < 4; ++u) wv[u] = *(const float4*)&W[kk + u][j4 * 4];
#pragma unroll
            for (int i = 0; i < 4; ++i) {
                acc[i][0] += a[i].x * wv[0].x + a[i].y * wv[1].x + a[i].z * wv[2].x + a[i].w * wv[3].x;
                acc[i][1] += a[i].x * wv[0].y + a[i].y * wv[1].y + a[i].z * wv[2].y + a[i].w * wv[3].y;
                acc[i][2] += a[i].x * wv[0].z + a[i].y * wv[1].z + a[i].z * wv[2].z + a[i].w * wv[3].z;
                acc[i][3] += a[i].x * wv[0].w + a[i].y * wv[1].w + a[i].z * wv[2].w + a[i].w * wv[3].w;
            }
        }
    }
#pragma unroll
    for (int i = 0; i < 4; ++i) {
        int e = e0 + e4 * 4 + i;
        int t = e & (NT - 1);
        float4 fv = *(const float4*)(f + (size_t)t * DIM + j4 * 4);
        float sp = tanhf(acc[i][0]) * fv.x + tanhf(acc[i][1]) * fv.y
                 + tanhf(acc[i][2]) * fv.z + tanhf(acc[i][3]) * fv.w;
#pragma unroll
        for (int off = 16; off > 0; off >>= 1) sp += __shfl_xor(sp, off, 64);
        if (j4 == 0 && e < Ea) sgl[e] = sp;
    }
}

// K6: select[t] = sum_k ft[agg_src[t+k*NT]] * s[t+k*NT].  One wave per target.
__global__ __launch_bounds__(256) void k_select(
    const int* __restrict__ agg_src, const float* __restrict__ ft,
    const float* __restrict__ sgl, float* __restrict__ sel, int Ea)
{
    int t = blockIdx.x * 4 + (threadIdx.x >> 6);
    int lane = threadIdx.x & 63;
    int cnt = (Ea - t + NT - 1) / NT;
    float ax = 0.f, ay = 0.f;
    for (int k = 0; k < cnt; ++k) {
        int e = t + k * NT;
        float sv = sgl[e];
        int src = agg_src[e];
        float2 vv = *(const float2*)(ft + (size_t)src * DIM + lane * 2);
        ax += sv * vv.x; ay += sv * vv.y;
    }
    *(float2*)(sel + (size_t)t * DIM + lane * 2) = make_float2(ax, ay);
}

// K7: scores = select @ emb[1:].T   (fp32 register-blocked, 64x64 tile)
__global__ __launch_bounds__(256) void k_scores(
    const float* __restrict__ sel, const float* __restrict__ emb,
    float* __restrict__ out, int NNT, int NODES)
{
    __shared__ float selT[DIM][TT + 4];   // [k][t]
    __shared__ float embT[DIM][NN + 4];   // [k][n]
    int tid = threadIdx.x;
    int t0 = blockIdx.x * TT;
    int n0 = blockIdx.y * NN;
    {
        int row = tid >> 2;        // 0..63
        int cq  = tid & 3;         // k-quarter
        const float* srow = sel + (size_t)(t0 + row) * DIM + cq * 32;
#pragma unroll
        for (int u = 0; u < 8; ++u) {
            float4 v = *(const float4*)(srow + u * 4);
            int k = cq * 32 + u * 4;
            selT[k+0][row] = v.x; selT[k+1][row] = v.y;
            selT[k+2][row] = v.z; selT[k+3][row] = v.w;
        }
        int nrow = 1 + n0 + row;
        const float* erow = emb + (size_t)nrow * DIM + cq * 32;
#pragma unroll
        for (int u = 0; u < 8; ++u) {
            float4 v = make_float4(0.f, 0.f, 0.f, 0.f);
            if (nrow < NODES) v = *(const float4*)(erow + u * 4);
            int k = cq * 32 + u * 4;
            embT[k+0][row] = v.x; embT[k+1][row] = v.y;
            embT[k+2][row] = v.z; embT[k+3][row] = v.w;
        }
    }
    __syncthreads();
    int tq = tid >> 5;   // 0..7 -> t = t0 + tq*8 + i
    int tn = tid & 31;   // n = n0 + tn + 32u
    float acc[8][2] = {};
#pragma unroll 2
    for (int k = 0; k < DIM; ++k) {
        float4 a0 = *(const float4*)&selT[k][tq * 8];
        float4 a1 = *(const float4*)&selT[k][tq * 8 + 4];
        float b0 = embT[k][tn];
        float b1 = embT[k][tn + 32];
        acc[0][0] += a0.x * b0; acc[0][1] += a0.x * b1;
        acc[1][0] += a0.y * b0; acc[1][1] += a0.y * b1;
        acc[2][0] += a0.z * b0; acc[2][1] += a0.z * b1;
        acc[3][0] += a0.w * b0; acc[3][1] += a0.w * b1;
        acc[4][0] += a1.x * b0; acc[4][1] += a1.x * b1;
        acc[5][0] += a1.y * b0; acc[5][1] += a1.y * b1;
        acc[6][0] += a1.z * b0; acc[6][1] += a1.z * b1;
        acc[7][0] += a1.w * b0; acc[7][1] += a1.w * b1;
    }
#pragma unroll
    for (int i = 0; i < 8; ++i) {
        size_t trow = (size_t)(t0 + tq * 8 + i) * NNT;
#pragma unroll
        for (int u = 0; u < 2; ++u) {
            int n = n0 + tn + 32 * u;
            if (n < NNT) out[trow + n] = acc[i][u];
        }
    }
}

extern "C" void kernel_launch(void* const* d_in, const int* in_sizes, int n_in,
                              void* d_out, int out_size, void* d_ws, size_t ws_size,
                              hipStream_t stream)
{
    const int*   iid       = (const int*)d_in[0];
    const int*   inter_src = (const int*)d_in[1];
    const int*   agg_src   = (const int*)d_in[3];
    const int*   agg_pid   = (const int*)d_in[5];
    const float* emb       = (const float*)d_in[7];
    const float* ln1_w     = (const float*)d_in[8];
    const float* ln1_b     = (const float*)d_in[9];
    const float* ln2_w     = (const float*)d_in[10];
    const float* ln2_b     = (const float*)d_in[11];
    const float* te        = (const float*)d_in[12];
    const float* pos       = (const float*)d_in[13];
    const float* Wq        = (const float*)d_in[14];
    const float* Wr        = (const float*)d_in[15];
    float* out = (float*)d_out;

    int Ni    = in_sizes[0];
    int Ea    = in_sizes[3];
    int NODES = in_sizes[7] / DIM;
    int NNT   = NODES - 1;

    char* w = (char*)d_ws;
    float* qkv   = (float*)w;  w += (size_t)Ni * DIM * sizeof(float);
    float* ft    = (float*)w;  w += (size_t)Ni * DIM * sizeof(float);
    float* meanb = (float*)w;  w += (size_t)NT * DIM * sizeof(float);
    float* fbuf  = (float*)w;  w += (size_t)NT * DIM * sizeof(float);
    float* sel   = (float*)w;  w += (size_t)NT * DIM * sizeof(float);
    float* sgl   = (float*)w;  w += (size_t)Ea * sizeof(float);

    k_qkv   <<<dim3((Ni + 3) / 4), dim3(256), 0, stream>>>(iid, emb, ln1_w, ln1_b, qkv, Ni);
    k_attn  <<<dim3((Ni + 3) / 4), dim3(256), 0, stream>>>(iid, inter_src, emb, qkv, ln2_w, ln2_b, ft, Ni);
    k_mean  <<<dim3(NT), dim3(256), 0, stream>>>(agg_src, ft, meanb, Ea);
    k_f     <<<dim3(NT / 2), dim3(256), 0, stream>>>(meanb, te, Wr, fbuf);
    k_edge  <<<dim3((Ea + K5_EDGES - 1) / K5_EDGES), dim3(256), 0, stream>>>(
                agg_src, agg_pid, ft, pos, Wq, fbuf, sgl, Ea);
    k_select<<<dim3(NT / 4), dim3(256), 0, stream>>>(agg_src, ft, sgl, sel, Ea);
    k_scores<<<dim3(NT / TT, (NNT + NN - 1) / NN), dim3(256), 0, stream>>>(
                sel, emb, out, NNT, NODES);
}

// Round 2
// 804.292 us; speedup vs baseline: 1.5779x; 1.5779x over previous
//
#include <hip/hip_runtime.h>
#include <hip/hip_bf16.h>

#define DIM 128
#define NT  2048

typedef __bf16 bfx8   __attribute__((ext_vector_type(8)));
typedef float  f32x16 __attribute__((ext_vector_type(16)));

static constexpr float SQRT_D      = 11.313708498984761f;   // sqrt(128)
static constexpr float INV_SQRT_DK = 0.08838834764831845f;  // 1/sqrt(128)
static constexpr float LN_EPS      = 1e-5f;

__device__ __forceinline__ float waveReduceSum(float v) {
#pragma unroll
    for (int off = 32; off > 0; off >>= 1) v += __shfl_xor(v, off, 64);
    return v;
}

__device__ __forceinline__ unsigned short f2bf(float f) {
    union { float f; unsigned int u; } v; v.f = f;
    unsigned int r = v.u + 0x7fffu + ((v.u >> 16) & 1u);
    return (unsigned short)(r >> 16);
}
__device__ __forceinline__ float2 upk(unsigned int u) {
    union { unsigned int u; float f; } a, b;
    a.u = u << 16; b.u = u & 0xffff0000u;
    return make_float2(a.f, b.f);
}
__device__ __forceinline__ bfx8 ldfrag(const void* p) {
    return __builtin_bit_cast(bfx8, *(const uint4*)p);
}
__device__ __forceinline__ f32x16 zero16() {
    f32x16 z;
#pragma unroll
    for (int i = 0; i < 16; ++i) z[i] = 0.f;
    return z;
}

// K0: casts — emb->bf16, pos->bf16, Wq -> transposed bf16 [128][256]
__global__ __launch_bounds__(256) void k_cast(
    const float* __restrict__ emb, const float* __restrict__ pos,
    const float* __restrict__ Wq, unsigned short* __restrict__ emb_bf,
    unsigned short* __restrict__ pos_bf, unsigned short* __restrict__ Wqt_bf,
    int nemb)
{
    int i4 = (blockIdx.x * 256 + threadIdx.x) * 4;
    if (i4 < nemb) {
        float4 v = *(const float4*)(emb + i4);
        *(ushort4*)(emb_bf + i4) = make_ushort4(f2bf(v.x), f2bf(v.y), f2bf(v.z), f2bf(v.w));
    }
    if (i4 < 200 * DIM) {
        float4 v = *(const float4*)(pos + i4);
        *(ushort4*)(pos_bf + i4) = make_ushort4(f2bf(v.x), f2bf(v.y), f2bf(v.z), f2bf(v.w));
    }
    if (i4 < 2 * DIM * DIM) {
#pragma unroll
        for (int c = 0; c < 4; ++c) {
            int i = i4 + c;
            int k = i >> 7, j = i & 127;
            Wqt_bf[j * 256 + k] = f2bf(Wq[i]);
        }
    }
}

// K1: x = emb[iid]*sqrt(D); qkv_bf = bf16(LN1(x)).  One wave per node.
__global__ __launch_bounds__(256) void k_qkv(
    const int* __restrict__ iid, const float* __restrict__ emb,
    const float* __restrict__ w, const float* __restrict__ b,
    unsigned short* __restrict__ qkv_bf, int Ni)
{
    int wid  = blockIdx.x * 4 + (threadIdx.x >> 6);
    int lane = threadIdx.x & 63;
    if (wid >= Ni) return;
    int id = iid[wid];
    float2 e2 = *(const float2*)(emb + (size_t)id * DIM + lane * 2);
    float x0 = e2.x * SQRT_D, x1 = e2.y * SQRT_D;
    float m = waveReduceSum(x0 + x1) * (1.0f / DIM);
    float d0 = x0 - m, d1 = x1 - m;
    float v = waveReduceSum(d0 * d0 + d1 * d1) * (1.0f / DIM);
    float r = rsqrtf(v + LN_EPS);
    float2 wv = *(const float2*)(w + lane * 2);
    float2 bv = *(const float2*)(b + lane * 2);
    float o0 = d0 * r * wv.x + bv.x, o1 = d1 * r * wv.y + bv.y;
    unsigned int o = (unsigned int)f2bf(o0) | ((unsigned int)f2bf(o1) << 16);
    *(unsigned int*)(qkv_bf + (size_t)wid * DIM + lane * 2) = o;
}

// K2: 8-edge attention + residual + LN2 -> ft_bf.  One wave per node.
__global__ __launch_bounds__(256) void k_attn(
    const int* __restrict__ iid, const int* __restrict__ inter_src,
    const float* __restrict__ emb, const unsigned short* __restrict__ qkv_bf,
    const float* __restrict__ w, const float* __restrict__ b,
    unsigned short* __restrict__ ft_bf, int Ni)
{
    int wid  = blockIdx.x * 4 + (threadIdx.x >> 6);
    int lane = threadIdx.x & 63;
    if (wid >= Ni) return;
    float2 q = upk(*(const unsigned int*)(qkv_bf + (size_t)wid * DIM + lane * 2));
    int srcv = 0;
    if (lane < 8) srcv = inter_src[wid + lane * Ni];
    float2 kv[8];
#pragma unroll
    for (int j = 0; j < 8; ++j) {
        int s = __shfl(srcv, j, 64);
        kv[j] = upk(*(const unsigned int*)(qkv_bf + (size_t)s * DIM + lane * 2));
    }
    float p[8];
#pragma unroll
    for (int j = 0; j < 8; ++j) p[j] = q.x * kv[j].x + q.y * kv[j].y;
#pragma unroll
    for (int off = 32; off > 0; off >>= 1) {
#pragma unroll
        for (int j = 0; j < 8; ++j) p[j] += __shfl_xor(p[j], off, 64);
    }
    float wx = 0.f, wy = 0.f, z = 0.f;
#pragma unroll
    for (int j = 0; j < 8; ++j) {
        float sc = __expf(fminf(fmaxf(p[j] * INV_SQRT_DK, -10.0f), 10.0f));
        wx += sc * kv[j].x; wy += sc * kv[j].y; z += sc;
    }
    float rz = 1.0f / z;
    int id = iid[wid];
    float2 e2 = *(const float2*)(emb + (size_t)id * DIM + lane * 2);
    float y0 = e2.x * SQRT_D + wx * rz;
    float y1 = e2.y * SQRT_D + wy * rz;
    float m = waveReduceSum(y0 + y1) * (1.0f / DIM);
    float d0 = y0 - m, d1 = y1 - m;
    float v = waveReduceSum(d0 * d0 + d1 * d1) * (1.0f / DIM);
    float r = rsqrtf(v + LN_EPS);
    float2 wv2 = *(const float2*)(w + lane * 2);
    float2 bv2 = *(const float2*)(b + lane * 2);
    float o0 = d0 * r * wv2.x + bv2.x, o1 = d1 * r * wv2.y + bv2.y;
    unsigned int o = (unsigned int)f2bf(o0) | ((unsigned int)f2bf(o1) << 16);
    *(unsigned int*)(ft_bf + (size_t)wid * DIM + lane * 2) = o;
}

// K3: per-target mean of gathered ft rows.  One block per target, 4 waves split k.
__global__ __launch_bounds__(256) void k_mean(
    const int* __restrict__ agg_src, const unsigned short* __restrict__ ft_bf,
    float* __restrict__ meanb, int Ea)
{
    int t = blockIdx.x;
    int wv = threadIdx.x >> 6, lane = threadIdx.x & 63;
    int cnt = (Ea - t + NT - 1) / NT;
    float ax = 0.f, ay = 0.f;
    for (int k = wv; k < cnt; k += 4) {
        int e = t + k * NT;
        int src = agg_src[e];
        float2 vv = upk(*(const unsigned int*)(ft_bf + (size_t)src * DIM + lane * 2));
        ax += vv.x; ay += vv.y;
    }
    __shared__ float red[4][DIM];
    red[wv][lane * 2] = ax; red[wv][lane * 2 + 1] = ay;
    __syncthreads();
    if (wv == 0) {
        float sx = red[0][lane*2] + red[1][lane*2] + red[2][lane*2] + red[3][lane*2];
        float sy = red[0][lane*2+1] + red[1][lane*2+1] + red[2][lane*2+1] + red[3][lane*2+1];
        float inv = 1.0f / (float)(cnt > 0 ? cnt : 1);
        *(float2*)(meanb + (size_t)t * DIM + lane * 2) = make_float2(sx * inv, sy * inv);
    }
}

// K4: f_T[j][t] = (concat(target_emb, mean[t]) @ Wr)[j]   (transposed output)
__global__ __launch_bounds__(256) void k_f(
    const float* __restrict__ meanb, const float* __restrict__ te,
    const float* __restrict__ Wr, float* __restrict__ f_T)
{
    int t = blockIdx.x * 2 + (threadIdx.x >> 7);
    int j = threadIdx.x & 127;
    float acc = 0.f;
#pragma unroll 4
    for (int k = 0; k < DIM; ++k) acc += te[k] * Wr[k * DIM + j];
    const float* mrow = meanb + (size_t)t * DIM;
#pragma unroll 4
    for (int k = 0; k < DIM; ++k) acc += mrow[k] * Wr[(DIM + k) * DIM + j];
    f_T[(size_t)j * NT + t] = acc;
}

// K5: per-edge  s[e] = sum_j tanh([ft_e,pos] @ Wq)_j * f[t(e)][j]  via MFMA.
// A = Wq^T (held in regs, 32-j strip per wave), B = 32 edge feature rows in
// XOR-swizzled LDS.  D[j][e] accumulators get tanh+dot in-register.
__global__ __launch_bounds__(256) void k_edge(
    const int* __restrict__ agg_src, const int* __restrict__ agg_pid,
    const unsigned short* __restrict__ ft_bf, const unsigned short* __restrict__ pos_bf,
    const unsigned short* __restrict__ Wqt_bf, const float* __restrict__ f_T,
    float* __restrict__ sgl, int ntiles, int gridn)
{
    __shared__ __align__(16) char B[32 * 512];
    __shared__ float red[4][32];
    int tid = threadIdx.x;
    int wid = tid >> 6, lane = tid & 63;
    int l31 = lane & 31, lh = lane >> 5;

    bfx8 wa[16];
    {
        const unsigned short* base = Wqt_bf + (wid * 32 + l31) * 256 + lh * 8;
#pragma unroll
        for (int kk = 0; kk < 16; ++kk) wa[kk] = ldfrag(base + kk * 16);
    }

    for (int tIdx = blockIdx.x; tIdx < ntiles; tIdx += gridn) {
        int e0 = tIdx * 32;
        __syncthreads();   // previous tile fully consumed (LDS B + red)
        {   // stage 32 edges x 512B, XOR-swizzled 16B slots
            int r = tid >> 3, pp = tid & 7;
            int e = e0 + r;
            int src = agg_src[e], pid = agg_pid[e];
#pragma unroll
            for (int c = 0; c < 4; ++c) {
                int s = pp * 4 + c;
                const unsigned short* g = (s < 16)
                    ? (ft_bf  + (size_t)src * DIM + s * 8)
                    : (pos_bf + (size_t)pid * DIM + (s - 16) * 8);
                *(uint4*)(B + r * 512 + ((s ^ r) << 4)) = *(const uint4*)g;
            }
        }
        __syncthreads();
        f32x16 acc = zero16();
#pragma unroll
        for (int kk = 0; kk < 16; ++kk) {
            int s = kk * 2 + lh;
            bfx8 bf = ldfrag(B + l31 * 512 + ((s ^ l31) << 4));
            acc = __builtin_amdgcn_mfma_f32_32x32x16_bf16(wa[kk], bf, acc, 0, 0, 0);
        }
        int e = e0 + l31;
        int t = e & (NT - 1);
        float partial = 0.f;
#pragma unroll
        for (int r = 0; r < 16; ++r) {
            int j = wid * 32 + (r & 3) + 8 * (r >> 2) + 4 * lh;
            float x = acc[r];
            float ex = __expf(2.0f * x);
            float th = (ex - 1.0f) / (ex + 1.0f);
            partial += th * f_T[(size_t)j * NT + t];
        }
        partial += __shfl_xor(partial, 32, 64);
        if (lane < 32) red[wid][l31] = partial;
        __syncthreads();
        if (tid < 32) sgl[e0 + tid] = red[0][tid] + red[1][tid] + red[2][tid] + red[3][tid];
    }
}

// K6: select[t] = sum_k ft[agg_src[t+k*NT]] * s[t+k*NT] -> bf16.  One wave/target.
__global__ __launch_bounds__(256) void k_select(
    const int* __restrict__ agg_src, const unsigned short* __restrict__ ft_bf,
    const float* __restrict__ sgl, unsigned short* __restrict__ sel_bf, int Ea)
{
    int t = blockIdx.x * 4 + (threadIdx.x >> 6);
    int lane = threadIdx.x & 63;
    int cnt = (Ea - t + NT - 1) / NT;
    float ax = 0.f, ay = 0.f;
    for (int k = 0; k < cnt; ++k) {
        int e = t + k * NT;
        float sv = sgl[e];
        float2 vv = upk(*(const unsigned int*)(ft_bf + (size_t)agg_src[e] * DIM + lane * 2));
        ax += sv * vv.x; ay += sv * vv.y;
    }
    unsigned int o = (unsigned int)f2bf(ax) | ((unsigned int)f2bf(ay) << 16);
    *(unsigned int*)(sel_bf + (size_t)t * DIM + lane * 2) = o;
}

// K7: scores = sel @ emb[1:].T  via MFMA.  A(sel) in regs; emb tiles through
// double-buffered XOR-swizzled LDS; fp32 stores (HBM-write-bound).
#define SNB  64
#define SNIT 8
__global__ __launch_bounds__(256) void k_scores(
    const unsigned short* __restrict__ sel_bf, const unsigned short* __restrict__ emb_bf,
    float* __restrict__ out, int NNT, int NODES)
{
    __shared__ __align__(16) char B[2][SNB * 256];
    int tid = threadIdx.x, wid = tid >> 6, lane = tid & 63;
    int l31 = lane & 31, lh = lane >> 5;

    bfx8 ka[8];
    {
        const unsigned short* base = sel_bf + (size_t)(blockIdx.x * 128 + wid * 32 + l31) * DIM + lh * 8;
#pragma unroll
        for (int kk = 0; kk < 8; ++kk) ka[kk] = ldfrag(base + kk * 16);
    }
    int n_start = blockIdx.y * (SNB * SNIT);
    int nit = (NNT - n_start + SNB - 1) / SNB;
    if (nit > SNIT) nit = SNIT;

    int sr = tid & 63;   // staging row
    int sq = tid >> 6;   // staging quarter
    {   // prologue: stage tile 0 -> buf 0
#pragma unroll
        for (int c = 0; c < 4; ++c) {
            int s = sq * 4 + c;
            int g = 1 + n_start + sr; if (g >= NODES) g = 0;
            *(uint4*)(B[0] + sr * 256 + ((s ^ (sr & 15)) << 4)) =
                *(const uint4*)(emb_bf + (size_t)g * DIM + s * 8);
        }
    }
    for (int it = 0; it < nit; ++it) {
        __syncthreads();
        int nb = n_start + it * SNB;
        uint4 st[4];
        bool more = (it + 1 < nit);
        if (more) {
            int nb2 = nb + SNB;
#pragma unroll
            for (int c = 0; c < 4; ++c) {
                int s = sq * 4 + c;
                int g = 1 + nb2 + sr; if (g >= NODES) g = 0;
                st[c] = *(const uint4*)(emb_bf + (size_t)g * DIM + s * 8);
            }
        }
        const char* buf = B[it & 1];
        f32x16 acc0 = zero16(), acc1 = zero16();
#pragma unroll
        for (int kk = 0; kk < 8; ++kk) {
            int s = kk * 2 + lh;
            int r0 = l31, r1 = 32 + l31;
            bfx8 b0 = ldfrag(buf + r0 * 256 + ((s ^ (r0 & 15)) << 4));
            bfx8 b1 = ldfrag(buf + r1 * 256 + ((s ^ (r1 & 15)) << 4));
            acc0 = __builtin_amdgcn_mfma_f32_32x32x16_bf16(ka[kk], b0, acc0, 0, 0, 0);
            acc1 = __builtin_amdgcn_mfma_f32_32x32x16_bf16(ka[kk], b1, acc1, 0, 0, 0);
        }
        if (more) {
            char* nxt = B[(it + 1) & 1];
#pragma unroll
            for (int c = 0; c < 4; ++c) {
                int s = sq * 4 + c;
                *(uint4*)(nxt + sr * 256 + ((s ^ (sr & 15)) << 4)) = st[c];
            }
        }
        int t_base = blockIdx.x * 128 + wid * 32 + 4 * lh;
#pragma unroll
        for (int r = 0; r < 16; ++r) {
            int trow = t_base + (r & 3) + 8 * (r >> 2);
            size_t rowoff = (size_t)trow * (size_t)NNT;
            int n0 = nb + l31;
            int n1 = nb + 32 + l31;
            if (n0 < NNT) out[rowoff + n0] = acc0[r];
            if (n1 < NNT) out[rowoff + n1] = acc1[r];
        }
    }
}

extern "C" void kernel_launch(void* const* d_in, const int* in_sizes, int n_in,
                              void* d_out, int out_size, void* d_ws, size_t ws_size,
                              hipStream_t stream)
{
    const int*   iid       = (const int*)d_in[0];
    const int*   inter_src = (const int*)d_in[1];
    const int*   agg_src   = (const int*)d_in[3];
    const int*   agg_pid   = (const int*)d_in[5];
    const float* emb       = (const float*)d_in[7];
    const float* ln1_w     = (const float*)d_in[8];
    const float* ln1_b     = (const float*)d_in[9];
    const float* ln2_w     = (const float*)d_in[10];
    const float* ln2_b     = (const float*)d_in[11];
    const float* te        = (const float*)d_in[12];
    const float* pos       = (const float*)d_in[13];
    const float* Wq        = (const float*)d_in[14];
    const float* Wr        = (const float*)d_in[15];
    float* out = (float*)d_out;

    int Ni    = in_sizes[0];
    int Ea    = in_sizes[3];
    int NODES = in_sizes[7] / DIM;
    int NNT   = NODES - 1;

    char* w = (char*)d_ws;
    unsigned short* qkv_bf = (unsigned short*)w; w += (size_t)Ni * DIM * 2;
    unsigned short* ft_bf  = (unsigned short*)w; w += (size_t)Ni * DIM * 2;
    unsigned short* emb_bf = (unsigned short*)w; w += (size_t)NODES * DIM * 2;
    unsigned short* pos_bf = (unsigned short*)w; w += (size_t)200 * DIM * 2;
    unsigned short* Wqt_bf = (unsigned short*)w; w += (size_t)2 * DIM * DIM * 2;
    unsigned short* sel_bf = (unsigned short*)w; w += (size_t)NT * DIM * 2;
    float* meanb = (float*)w; w += (size_t)NT * DIM * 4;
    float* f_T   = (float*)w; w += (size_t)DIM * NT * 4;
    float* sgl   = (float*)w; w += (size_t)Ea * 4;

    int nemb = NODES * DIM;
    int castBlocks = (nemb / 4 + 255) / 256;
    k_cast  <<<dim3(castBlocks), dim3(256), 0, stream>>>(emb, pos, Wq, emb_bf, pos_bf, Wqt_bf, nemb);
    k_qkv   <<<dim3((Ni + 3) / 4), dim3(256), 0, stream>>>(iid, emb, ln1_w, ln1_b, qkv_bf, Ni);
    k_attn  <<<dim3((Ni + 3) / 4), dim3(256), 0, stream>>>(iid, inter_src, emb, qkv_bf, ln2_w, ln2_b, ft_bf, Ni);
    k_mean  <<<dim3(NT), dim3(256), 0, stream>>>(agg_src, ft_bf, meanb, Ea);
    k_f     <<<dim3(NT / 2), dim3(256), 0, stream>>>(meanb, te, Wr, f_T);
    int ntiles = Ea / 32;
    int gridn  = ntiles < 2048 ? ntiles : 2048;
    k_edge  <<<dim3(gridn), dim3(256), 0, stream>>>(agg_src, agg_pid, ft_bf, pos_bf, Wqt_bf, f_T, sgl, ntiles, gridn);
    k_select<<<dim3(NT / 4), dim3(256), 0, stream>>>(agg_src, ft_bf, sgl, sel_bf, Ea);
    k_scores<<<dim3(16, (NNT + SNB * SNIT - 1) / (SNB * SNIT)), dim3(256), 0, stream>>>(sel_bf, emb_bf, out, NNT, NODES);
}